// Round 5
// baseline (283.437 us; speedup 1.0000x reference)
//
#include <hip/hip_runtime.h>

typedef short short8 __attribute__((ext_vector_type(8)));
typedef float f32x4 __attribute__((ext_vector_type(4)));
typedef unsigned short u16;
typedef u16 u16x8 __attribute__((ext_vector_type(8)));
typedef unsigned int u32;
typedef u32 u32x4 __attribute__((ext_vector_type(4)));

#define NTOK 4096
#define CDIM 256
#define TQ 64
#define TJ 32
#define NT (NTOK / TJ)
#define LOG2E 1.44269504088896f

__device__ __forceinline__ u16 f2bf(float f) {
    unsigned u = __float_as_uint(f);
    unsigned r = (u + 0x7fffu + ((u >> 16) & 1u)) >> 16;   // RNE
    return (u16)r;
}
__device__ __forceinline__ float bf2f(u16 h) { return __uint_as_float(((unsigned)h) << 16); }
__device__ __forceinline__ u32 pk_bf16(float a, float b) {
    u32 w;
    asm("v_cvt_pk_bf16_f32 %0, %1, %2" : "=v"(w) : "v"(a), "v"(b));
    return w;
}

// ---------------------------------------------------------------------------
// W convert: rows 0-31 Wq, 32-63 Wk, 64-319 Wv -> whi/wlo bf16 [320][256]
// ---------------------------------------------------------------------------
__global__ __launch_bounds__(256)
void wconv(const float* __restrict__ Wq, const float* __restrict__ Wk,
           const float* __restrict__ Wv, u16* __restrict__ whi, u16* __restrict__ wlo) {
    const int row = blockIdx.x;
    const int col = threadIdx.x;
    float v;
    if (row < 32)       v = Wq[row * 256 + col];
    else if (row < 64)  v = Wk[(row - 32) * 256 + col];
    else                v = Wv[(row - 64) * 256 + col];
    u16 h = f2bf(v);
    whi[row * 256 + col] = h;
    wlo[row * 256 + col] = f2bf(v - bf2f(h));
}

// ---------------------------------------------------------------------------
// Fused projection via MFMA (hi/lo 3-term). Block: 64 tokens, all 320 out ch.
// Wave w owns m-tiles 5w..5w+4 (mt 0-1=Q, 2-3=K, 4-19=V), 4 n-tiles.
// x-tile staged once in LDS transposed (token-major) as bf16 hi/lo.
// grid (64, 4) = 256 blocks.
// ---------------------------------------------------------------------------
__global__ __launch_bounds__(256, 1)
void proj_fused(const float* __restrict__ x,
                const u16* __restrict__ whi, const u16* __restrict__ wlo,
                const float* __restrict__ bq, const float* __restrict__ bk,
                const float* __restrict__ bv,
                u16* __restrict__ qhi, u16* __restrict__ qlo,
                u16* __restrict__ khi, u16* __restrict__ klo,
                u16* __restrict__ vbf) {
    __shared__ __attribute__((aligned(16))) u16 lxh[64][260];
    __shared__ __attribute__((aligned(16))) u16 lxl[64][260];
    const int b  = blockIdx.y;
    const int n0 = blockIdx.x * 64;
    const int t  = threadIdx.x;
    const int w  = t >> 6;
    const int l  = t & 63;
    const int cl = l & 15;
    const int kg = l >> 4;

    // ---- stage x-tile (256 c x 64 n) transposed to [n][c] bf16 hi/lo
    const int sn = (t & 15) * 4;
    const int sc = t >> 4;
#pragma unroll
    for (int cc = 0; cc < 16; cc++) {
        const int c = sc + cc * 16;
        const f32x4 xv = *(const f32x4*)&x[((size_t)(b * CDIM + c)) * NTOK + n0 + sn];
#pragma unroll
        for (int i = 0; i < 4; i++) {
            u16 hh = f2bf(xv[i]);
            lxh[sn + i][c] = hh;
            lxl[sn + i][c] = f2bf(xv[i] - bf2f(hh));
        }
    }
    __syncthreads();

    f32x4 acc[5][4];
    const f32x4 fz = {0.f, 0.f, 0.f, 0.f};
#pragma unroll
    for (int i = 0; i < 5; i++)
#pragma unroll
        for (int nt = 0; nt < 4; nt++) acc[i][nt] = fz;

#pragma unroll 2
    for (int ks = 0; ks < 8; ks++) {
        const int k0 = ks * 32;
        short8 bh[4], bl[4];
#pragma unroll
        for (int nt = 0; nt < 4; nt++) {
            bh[nt] = *(const short8*)&lxh[nt * 16 + cl][k0 + kg * 8];
            bl[nt] = *(const short8*)&lxl[nt * 16 + cl][k0 + kg * 8];
        }
#pragma unroll
        for (int i = 0; i < 5; i++) {
            const int mt = w * 5 + i;
            const size_t wb = (size_t)(mt * 16 + cl) * 256 + k0 + kg * 8;
            const short8 ah = *(const short8*)&whi[wb];
            const short8 al = *(const short8*)&wlo[wb];
#pragma unroll
            for (int nt = 0; nt < 4; nt++) {
                acc[i][nt] = __builtin_amdgcn_mfma_f32_16x16x32_bf16(ah, bh[nt], acc[i][nt], 0, 0, 0);
                acc[i][nt] = __builtin_amdgcn_mfma_f32_16x16x32_bf16(ah, bl[nt], acc[i][nt], 0, 0, 0);
                acc[i][nt] = __builtin_amdgcn_mfma_f32_16x16x32_bf16(al, bh[nt], acc[i][nt], 0, 0, 0);
            }
        }
    }

    // ---- epilogue: bias, split/convert, store
#pragma unroll
    for (int i = 0; i < 5; i++) {
        const int mt = w * 5 + i;
#pragma unroll
        for (int nt = 0; nt < 4; nt++) {
            const int n = n0 + nt * 16 + cl;
#pragma unroll
            for (int r = 0; r < 4; r++) {
                const int m = kg * 4 + r;
                float v = acc[i][nt][r];
                if (mt < 2) {
                    const int ch = mt * 16 + m;
                    v += bq[ch];
                    u16 hh = f2bf(v);
                    qhi[((size_t)(b * NTOK + n)) * 32 + ch] = hh;
                    qlo[((size_t)(b * NTOK + n)) * 32 + ch] = f2bf(v - bf2f(hh));
                } else if (mt < 4) {
                    const int ch = (mt - 2) * 16 + m;
                    v += bk[ch];
                    u16 hh = f2bf(v);
                    khi[((size_t)(b * NTOK + n)) * 32 + ch] = hh;
                    klo[((size_t)(b * NTOK + n)) * 32 + ch] = f2bf(v - bf2f(hh));
                } else {
                    const int c2 = (mt - 4) * 16 + m;
                    vbf[((size_t)(b * CDIM + c2)) * NTOK + n] = f2bf(v + bv[c2]);
                }
            }
        }
    }
}

// ---------------------------------------------------------------------------
// Fused flash attention. Block = 4 waves, TQ=64 queries, ONE HALF (h) of the
// 256 channels. Wave w: q-tile w (16 q), 128 c. V comes straight from global
// (L2-resident) into MFMA A-fragments, reg-double-buffered. LDS: K only.
// ---------------------------------------------------------------------------
__global__ __launch_bounds__(256, 2)
void attn_mfma(const u16* __restrict__ qhi, const u16* __restrict__ qlo,
               const u16* __restrict__ khi, const u16* __restrict__ klo,
               const u16* __restrict__ vbf, const float* __restrict__ x,
               float* __restrict__ out) {
    __shared__ __attribute__((aligned(16))) u16 lkh[2][TJ][32];
    __shared__ __attribute__((aligned(16))) u16 lkl[2][TJ][32];
    __shared__ __attribute__((aligned(16))) float lt[4][16][20];

    // XCD decode: (b,h) fixed per XCD -> V-half (1MB) + K resident in that L2
    const int lin = blockIdx.x;
    const int p  = lin & 7;
    const int b  = p >> 1;
    const int h  = p & 1;
    const int qb = lin >> 3;
    const int i0 = qb * TQ;
    const int t  = threadIdx.x;
    const int w  = t >> 6;
    const int l  = t & 63;
    const int cl = l & 15;
    const int kg = l >> 4;

    // Q B-fragments
    const int iq = i0 + w * 16 + cl;
    const short8 qh = *(const short8*)&qhi[((size_t)(b * NTOK + iq)) * 32 + kg * 8];
    const short8 ql = *(const short8*)&qlo[((size_t)(b * NTOK + iq)) * 32 + kg * 8];

    // K staging (LDS, hi/lo, chunk-swizzled) — verified scheme
    const int kj  = (t & 127) >> 2;
    const int kch = t & 3;
    const u16* ksrcbase = (t < 128) ? khi : klo;
    const u16* ksrc = &ksrcbase[((size_t)(b * NTOK + kj)) * 32 + kch * 8];
    u16x8 kreg;
    auto kload = [&](int tt) { kreg = *(const u16x8*)&ksrc[(size_t)(tt * TJ) * 32]; };
    auto kwrite = [&](int buf) {
        int ph = kch ^ ((kj >> 2) & 3);
        u16* kd = (t < 128) ? &lkh[buf][kj][ph * 8] : &lkl[buf][kj][ph * 8];
        *(u16x8*)kd = kreg;
    };

    // V A-fragments from global: row c = h*128 + ct*16 + cl, k-chunk kg
    const u16* vrow = &vbf[((size_t)(b * CDIM + h * 128 + cl)) * NTOK + kg * 8];
    u16x8 vba[8], vbb[8];
    auto vload = [&](u16x8 (&dst)[8], int tt) {
        const int j0 = tt * TJ;
#pragma unroll
        for (int ct = 0; ct < 8; ct++)
            dst[ct] = *(const u16x8*)&vrow[(size_t)ct * 16 * NTOK + j0];
    };

    f32x4 acc[8];
    const f32x4 fz = {0.f, 0.f, 0.f, 0.f};
#pragma unroll
    for (int ct = 0; ct < 8; ct++) acc[ct] = fz;

    float m_r = -1.0e30f, l_r = 0.f;   // l_r: per-lane partial (reduced at end)

    const int a0 = (((kg << 1) & 3) * 16 + cl) * 4;
    const int a1 = ((((kg << 1) + 1) & 3) * 16 + cl) * 4;
    const bool lo2 = (kg < 2);

    kload(0); kwrite(0); vload(vba, 0);
    __syncthreads();

    auto body = [&](int tt, u16x8 (&vcur)[8], u16x8 (&vnxt)[8]) {
        const int cur = tt & 1;
        const int nxt = cur ^ 1;
        const bool pre = (tt + 1 < NT);
        if (pre) { kload(tt + 1); vload(vnxt, tt + 1); }   // issue loads early

        // ---- scores (swapped): St[j][q], lane q=cl
        f32x4 s0 = fz, s1 = fz;
        {
            const int j0r = cl;
            const int ph0 = (kg ^ ((j0r >> 2) & 3)) * 8;
            short8 kh = *(const short8*)&lkh[cur][j0r][ph0];
            short8 kl = *(const short8*)&lkl[cur][j0r][ph0];
            s0 = __builtin_amdgcn_mfma_f32_16x16x32_bf16(kh, qh, s0, 0, 0, 0);
            s0 = __builtin_amdgcn_mfma_f32_16x16x32_bf16(kl, qh, s0, 0, 0, 0);
            s0 = __builtin_amdgcn_mfma_f32_16x16x32_bf16(kh, ql, s0, 0, 0, 0);
        }
        {
            const int j1r = 16 + cl;
            const int ph1 = (kg ^ ((j1r >> 2) & 3)) * 8;
            short8 kh = *(const short8*)&lkh[cur][j1r][ph1];
            short8 kl = *(const short8*)&lkl[cur][j1r][ph1];
            s1 = __builtin_amdgcn_mfma_f32_16x16x32_bf16(kh, qh, s1, 0, 0, 0);
            s1 = __builtin_amdgcn_mfma_f32_16x16x32_bf16(kl, qh, s1, 0, 0, 0);
            s1 = __builtin_amdgcn_mfma_f32_16x16x32_bf16(kh, ql, s1, 0, 0, 0);
        }

        // ---- in-lane softmax (per-lane q = cl)
        float tmax = fmaxf(fmaxf(fmaxf(s0[0], s0[1]), fmaxf(s0[2], s0[3])),
                           fmaxf(fmaxf(s1[0], s1[1]), fmaxf(s1[2], s1[3])));
        tmax = fmaxf(tmax, __shfl_xor(tmax, 16));
        tmax = fmaxf(tmax, __shfl_xor(tmax, 32));

        if (__any(tmax > m_r + 8.f)) {          // defer-max rescale event
            float mn = fmaxf(m_r, tmax);
            float f  = exp2f((m_r - mn) * LOG2E);
            m_r = mn;
            l_r *= f;
#pragma unroll
            for (int ct = 0; ct < 8; ct++) acc[ct] *= f;
        }
        const float mm = m_r * LOG2E;
        float p00 = exp2f(fmaf(s0[0], LOG2E, -mm));
        float p01 = exp2f(fmaf(s0[1], LOG2E, -mm));
        float p02 = exp2f(fmaf(s0[2], LOG2E, -mm));
        float p03 = exp2f(fmaf(s0[3], LOG2E, -mm));
        float p10 = exp2f(fmaf(s1[0], LOG2E, -mm));
        float p11 = exp2f(fmaf(s1[1], LOG2E, -mm));
        float p12 = exp2f(fmaf(s1[2], LOG2E, -mm));
        float p13 = exp2f(fmaf(s1[3], LOG2E, -mm));
        l_r += ((p00 + p01) + (p02 + p03)) + ((p10 + p11) + (p12 + p13));

        // ---- pack to bf16 pairs, exchange to B-fragment (k = j)
        u32 w0 = pk_bf16(p00, p01);
        u32 w1 = pk_bf16(p02, p03);
        u32 w2 = pk_bf16(p10, p11);
        u32 w3 = pk_bf16(p12, p13);
        u32 y0a = __builtin_amdgcn_ds_bpermute(a0, w0);
        u32 y0b = __builtin_amdgcn_ds_bpermute(a0, w2);
        u32 y1a = __builtin_amdgcn_ds_bpermute(a0, w1);
        u32 y1b = __builtin_amdgcn_ds_bpermute(a0, w3);
        u32 y2a = __builtin_amdgcn_ds_bpermute(a1, w0);
        u32 y2b = __builtin_amdgcn_ds_bpermute(a1, w2);
        u32 y3a = __builtin_amdgcn_ds_bpermute(a1, w1);
        u32 y3b = __builtin_amdgcn_ds_bpermute(a1, w3);
        u32x4 bw;
        bw[0] = lo2 ? y0a : y0b;
        bw[1] = lo2 ? y1a : y1b;
        bw[2] = lo2 ? y2a : y2b;
        bw[3] = lo2 ? y3a : y3b;
        const short8 pfrag = __builtin_bit_cast(short8, bw);

        // ---- PV over this block's c-half: V A-frags from registers
#pragma unroll
        for (int ct = 0; ct < 8; ct++)
            acc[ct] = __builtin_amdgcn_mfma_f32_16x16x32_bf16(
                __builtin_bit_cast(short8, vcur[ct]), pfrag, acc[ct], 0, 0, 0);

        if (pre) kwrite(nxt);
        __syncthreads();
    };

    for (int tt = 0; tt < NT; tt += 2) {
        body(tt,     vba, vbb);
        body(tt + 1, vbb, vba);
    }

    // ---- reduce l across kg groups, epilogue
    l_r += __shfl_xor(l_r, 16);
    l_r += __shfl_xor(l_r, 32);
    const float linv = 1.f / l_r;
    const int c_r = l >> 2;
    const int q0  = (l & 3) * 4;
#pragma unroll 1
    for (int ct = 0; ct < 8; ct++) {
#pragma unroll
        for (int r = 0; r < 4; r++)
            lt[w][kg * 4 + r][cl] = acc[ct][r] * linv;
        __syncthreads();
        const f32x4 vv = *(const f32x4*)&lt[w][c_r][q0];
        const int c = h * 128 + ct * 16 + c_r;
        const size_t base = ((size_t)(b * CDIM + c)) * NTOK + i0 + w * 16 + q0;
        const f32x4 xv = *(const f32x4*)&x[base];
        f32x4 o;
#pragma unroll
        for (int ii = 0; ii < 4; ii++) o[ii] = vv[ii] + xv[ii];
        *(f32x4*)&out[base] = o;
        __syncthreads();
    }
}

// ---------------------------------------------------------------------------
extern "C" void kernel_launch(void* const* d_in, const int* in_sizes, int n_in,
                              void* d_out, int out_size, void* d_ws, size_t ws_size,
                              hipStream_t stream) {
    const float* x  = (const float*)d_in[0];
    const float* Wq = (const float*)d_in[1];
    const float* bq = (const float*)d_in[2];
    const float* Wk = (const float*)d_in[3];
    const float* bk = (const float*)d_in[4];
    const float* Wv = (const float*)d_in[5];
    const float* bv = (const float*)d_in[6];
    float* out = (float*)d_out;

    u16* qhi = (u16*)d_ws;                              // [4][4096][32]
    u16* qlo = qhi + (size_t)4 * NTOK * 32;
    u16* khi = qlo + (size_t)4 * NTOK * 32;
    u16* klo = khi + (size_t)4 * NTOK * 32;
    u16* vbf = klo + (size_t)4 * NTOK * 32;             // [4][256][4096]
    u16* whi = vbf + (size_t)4 * CDIM * NTOK;           // [320][256]
    u16* wlo = whi + (size_t)320 * 256;

    wconv<<<dim3(320), 256, 0, stream>>>(Wq, Wk, Wv, whi, wlo);
    proj_fused<<<dim3(64, 4), 256, 0, stream>>>(x, whi, wlo, bq, bk, bv,
                                                qhi, qlo, khi, klo, vbf);
    attn_mfma<<<dim3(512), 256, 0, stream>>>(qhi, qlo, khi, klo, vbf, x, out);
}